// Round 1
// baseline (250.724 us; speedup 1.0000x reference)
//
#include <hip/hip_runtime.h>

typedef __bf16 bf16;
typedef __bf16 bf16x4 __attribute__((ext_vector_type(4)));
typedef __bf16 bf16x8 __attribute__((ext_vector_type(8)));
typedef float f32x4 __attribute__((ext_vector_type(4)));

#define T_SEQ 2048
#define QK_LD 2048

extern "C" __device__ float __ocml_native_exp2_f32(float);   // raw v_exp_f32

#define GLOAD16(gp, lp)                                                        \
  __builtin_amdgcn_global_load_lds(                                            \
      (const __attribute__((address_space(1))) unsigned int*)(gp),             \
      (__attribute__((address_space(3))) unsigned int*)(lp), 16, 0, 0)

// ---------------------------------------------------------------------------
// Fused prep (one dispatch, 256-thr blocks):
//   blocks [0, 8192)        : x (fp32, 8192x1024) -> xb bf16
//   blocks [8192, 8192+3072): W_qkv (1024x3072) -> wtq (3072x1024) bf16
//   blocks [+3072, +4096)   : W_out (1024x1024) -> wto (1024x1024) bf16
// ---------------------------------------------------------------------------
__global__ void prep_kernel(const float* __restrict__ x, bf16* __restrict__ xb,
                            const float* __restrict__ Wq, bf16* __restrict__ Wtq,
                            const float* __restrict__ Wo, bf16* __restrict__ Wto) {
    __shared__ float tile[32][33];
    const int t = threadIdx.x;
    if (blockIdx.x < 8192) {
        const int i = (blockIdx.x * 256 + t) * 4;
        const float4 f = *(const float4*)(x + i);
        bf16x4 o;
        o.x = (bf16)f.x; o.y = (bf16)f.y; o.z = (bf16)f.z; o.w = (bf16)f.w;
        *(bf16x4*)(xb + i) = o;
        return;
    }
    const int bid = blockIdx.x - 8192;            // [0, 4096)
    const int xblk = bid & 127, yblk = bid >> 7;  // 128 x 32 tiles of 32x32
    const bool isQ = xblk < 96;
    const float* W = isQ ? Wq : Wo;
    bf16* Wt = isQ ? Wtq : Wto;
    const int C = isQ ? 3072 : 1024;
    const int R = 1024;
    const int bx = (isQ ? xblk : (xblk - 96)) * 32;
    const int by = yblk * 32;
    const int tx = t & 31, ty = t >> 5;
#pragma unroll
    for (int i = 0; i < 32; i += 8)
        tile[ty + i][tx] = W[(size_t)(by + ty + i) * C + bx + tx];
    __syncthreads();
#pragma unroll
    for (int i = 0; i < 32; i += 8)
        Wt[(size_t)(bx + ty + i) * R + by + tx] = (bf16)tile[tx][ty + i];
}

// ---------------------------------------------------------------------------
// NEW: 256x256 8-phase GEMM (T2+T3+T4+T5 per guide §5/§5.5).
//   C[M,N] = A[M,K]*Bt[N,K]^T (+bias), bf16 in, fp32 acc.
//   512 thr = 8 waves (2M x 4N); BK=64; LDS 128 KiB (2 dbuf x {A,B} x 2 halves
//   x 128x64 bf16). global_load_lds staging: linear LDS dest, XOR-swizzle
//   (c ^= row&7, 16B chunks) applied on the GLOBAL source (rule #21), so
//   ds_read_b128 fragment reads are conflict-free.
//   K-tile = 4 quadrant phases (A0B0, A1B0, A0B1, A1B1); phase p of tile t
//   stages half-tile p of tile t+1 (same order) -> counted waits:
//   steady vmcnt(4) at phases 0/1/3; last tile drains 2 -> 0.
//   Raw s_barrier (NOT __syncthreads: that drains vmcnt(0) = the m97 stall).
//   s_setprio(1) around each 16-MFMA cluster (T5, pays only in 8-phase).
// ---------------------------------------------------------------------------
template <bool OUT_BF16, bool SPLIT_V>
__global__ __launch_bounds__(512, 2)
void gemm256(const bf16* __restrict__ A, const bf16* __restrict__ Bt,
             const float* __restrict__ bias, void* __restrict__ Cout,
             bf16* __restrict__ Vtb, int M, int N, int K, int ldC) {
    __shared__ bf16 sm[65536];   // 128 KiB

    const int t = threadIdx.x;
    const int lane = t & 63, quad = lane >> 4, l16 = lane & 15;
    const int wv = t >> 6;
    const int wm = (wv >> 2) * 64;   // row base within an A half (2 M-wave-groups)
    const int wn = (wv & 3) * 32;    // row base within a B half (4 N-wave-groups)
    const long m0 = (long)blockIdx.y * 256;
    const long n0 = (long)blockIdx.x * 256;
    (void)M; (void)N;

    f32x4 acc[2][2][4][2] = {};      // [mq][nq][i][j]

    // --- staging source coords: linear chunk l = q*512 + t ------------------
    // row = q*64 + (t>>3); stored chunk c' = t&7 holds logical c = c'^(row&7)
    const int srow = t >> 3;
    const int scol = ((t & 7) ^ ((t >> 3) & 7)) * 8;
    const bf16* agp = A  + (m0 + srow) * (long)K + scol;
    const bf16* bgp = Bt + (n0 + srow) * (long)K + scol;
    const long rowK64  = (long)64 * K;
    const long rowK128 = (long)128 * K;
    bf16* ldst = sm + wv * 512;      // + buf*32768 + oper*16384 + half*8192 + q*4096

    auto stage = [&](int buf, int oper, int half, int kt) {
        const bf16* src = (oper ? bgp : agp) + (long)kt * 64 + (half ? rowK128 : 0);
        bf16* dst = ldst + buf * 32768 + oper * 16384 + half * 8192;
        GLOAD16(src, dst);                      // rows [0,64) of the half
        GLOAD16(src + rowK64, dst + 4096);      // rows [64,128)
    };

    // --- fragment LDS offsets (within a half base) --------------------------
    int offA[4][2], offB[2][2];
#pragma unroll
    for (int i = 0; i < 4; ++i)
#pragma unroll
        for (int ks = 0; ks < 2; ++ks) {
            const int r = wm + i * 16 + l16;
            offA[i][ks] = r * 64 + (((ks * 4 + quad) ^ (r & 7)) << 3);
        }
#pragma unroll
    for (int j = 0; j < 2; ++j)
#pragma unroll
        for (int ks = 0; ks < 2; ++ks) {
            const int r = wn + j * 16 + l16;
            offB[j][ks] = r * 64 + (((ks * 4 + quad) ^ (r & 7)) << 3);
        }

#define PHASE(BUF, MQ, NQ, DOSTAGE, SOP, SHF, SKT, WAITSTR) do {               \
    const bf16* sb_  = sm + (BUF) * 32768;                                     \
    const bf16* sa_  = sb_ + (MQ) * 8192;                                      \
    const bf16* sbb_ = sb_ + 16384 + (NQ) * 8192;                              \
    bf16x8 af_[2][4], bv_[2][2];                                               \
    _Pragma("unroll") for (int ks = 0; ks < 2; ++ks) {                         \
        _Pragma("unroll") for (int i = 0; i < 4; ++i)                          \
            af_[ks][i] = *(const bf16x8*)(sa_ + offA[i][ks]);                  \
        _Pragma("unroll") for (int j = 0; j < 2; ++j)                          \
            bv_[ks][j] = *(const bf16x8*)(sbb_ + offB[j][ks]);                 \
    }                                                                          \
    if (DOSTAGE) stage((BUF) ^ 1, SOP, SHF, SKT);                              \
    __builtin_amdgcn_s_barrier();                                              \
    __builtin_amdgcn_s_setprio(1);                                             \
    _Pragma("unroll") for (int ks = 0; ks < 2; ++ks)                           \
        _Pragma("unroll") for (int i = 0; i < 4; ++i)                          \
            _Pragma("unroll") for (int j = 0; j < 2; ++j)                      \
                acc[MQ][NQ][i][j] = __builtin_amdgcn_mfma_f32_16x16x32_bf16(   \
                    bv_[ks][j], af_[ks][i], acc[MQ][NQ][i][j], 0, 0, 0);       \
    __builtin_amdgcn_s_setprio(0);                                             \
    asm volatile(WAITSTR ::: "memory");                                        \
    __builtin_amdgcn_s_barrier();                                              \
    __builtin_amdgcn_sched_barrier(0);                                         \
} while (0)

    const int nkt = K >> 6;          // K-tiles of 64

    // prologue: stage tile 0 (order A0,B0,A1,B1), need first 4 loads landed
    stage(0, 0, 0, 0);
    stage(0, 1, 0, 0);
    stage(0, 0, 1, 0);
    stage(0, 1, 1, 0);
    asm volatile("s_waitcnt vmcnt(4)" ::: "memory");
    __builtin_amdgcn_s_barrier();
    __builtin_amdgcn_sched_barrier(0);

    for (int kt = 0; kt < nkt - 1; ++kt) {
        const int buf = kt & 1;
        const int kn = kt + 1;
        PHASE(buf, 0, 0, true, 0, 0, kn, "s_waitcnt vmcnt(4)");
        PHASE(buf, 1, 0, true, 1, 0, kn, "s_waitcnt vmcnt(4)");
        PHASE(buf, 0, 1, true, 0, 1, kn, "");
        PHASE(buf, 1, 1, true, 1, 1, kn, "s_waitcnt vmcnt(4)");
    }
    {   // last tile: no staging; drain counted 2 -> 0
        const int buf = (nkt - 1) & 1;
        PHASE(buf, 0, 0, false, 0, 0, 0, "s_waitcnt vmcnt(2)");
        PHASE(buf, 1, 0, false, 0, 0, 0, "s_waitcnt vmcnt(0)");
        PHASE(buf, 0, 1, false, 0, 0, 0, "");
        PHASE(buf, 1, 1, false, 0, 0, 0, "");
    }
#undef PHASE

    // --- epilogue (same swapped-D mapping as before: col=m via l16, row=n) --
    bf16*  Cb = (bf16*)Cout;
    float* Cf = (float*)Cout;
    const bool vblock = SPLIT_V && (n0 >= 2048);
#pragma unroll
    for (int mq = 0; mq < 2; ++mq)
#pragma unroll
    for (int i = 0; i < 4; ++i) {
        const long gm = m0 + mq * 128 + wm + i * 16 + l16;
#pragma unroll
        for (int nq = 0; nq < 2; ++nq)
#pragma unroll
        for (int j = 0; j < 2; ++j) {
            const long n = n0 + nq * 128 + wn + j * 16 + quad * 4;
            const float4 bv = *(const float4*)(bias + n);
            float v[4];
#pragma unroll
            for (int r = 0; r < 4; ++r) v[r] = acc[mq][nq][i][j][r] + (&bv.x)[r];
            if (vblock) {
                const int bb = (int)(gm >> 11), tok = (int)(gm & 2047);
                const int nv = (int)(n - 2048);
                const int h = nv >> 6, d0 = nv & 63;
                bf16* dst = Vtb + ((size_t)(bb * 16 + h) * 64 + d0) * T_SEQ + tok;
#pragma unroll
                for (int r = 0; r < 4; ++r) dst[(size_t)r * T_SEQ] = (bf16)v[r];
            } else if (OUT_BF16) {
                bf16x4 o;
#pragma unroll
                for (int r = 0; r < 4; ++r) o[r] = (bf16)v[r];
                *(bf16x4*)(Cb + gm * ldC + n) = o;
            } else {
                float4 o;
#pragma unroll
                for (int r = 0; r < 4; ++r) (&o.x)[r] = v[r];
                *(float4*)(Cf + gm * ldC + n) = o;
            }
        }
    }
}

// ---------------------------------------------------------------------------
// OLD 128x128 GEMM — kept for the output projection (N=1024: a 256² grid
// would be only 128 blocks = half-idle GPU). [r6/r9 verbatim]
// ---------------------------------------------------------------------------
template <bool OUT_BF16, bool SPLIT_V>
__global__ __launch_bounds__(256, 3)
void gemm_bt(const bf16* __restrict__ A, const bf16* __restrict__ Bt,
             const float* __restrict__ bias, void* __restrict__ Cout,
             bf16* __restrict__ Vtb, int M, int N, int K, int ldC) {
    __shared__ bf16 sm[16384];   // 2 bufs x (A 4096 + B 4096 elems) = 32 KB

    const int t = threadIdx.x;
    const int lane = t & 63, quad = lane >> 4, l16 = lane & 15;
    const int wave = t >> 6;
    const int wm = (wave >> 1) * 64;
    const int wn = (wave & 1) * 64;
    const long m0 = (long)blockIdx.y * 128;
    const long n0 = (long)blockIdx.x * 128;

    f32x4 acc[4][4] = {};

    const int sr = t >> 2, sc = t & 3;
    const int swz  = (sr * 4 + (sc ^ ((sr >> 1) & 3))) * 8;
    const int swz2 = ((sr + 64) * 4 + (sc ^ ((sr >> 1) & 3))) * 8;
    const bf16* agp = A  + (m0 + sr) * (long)K + sc * 8;
    const bf16* bgp = Bt + (n0 + sr) * (long)K + sc * 8;
    const long rowK = (long)64 * K;

    int offA[4], offB[4];
#pragma unroll
    for (int i = 0; i < 4; ++i) {
        const int row = wm + i * 16 + l16;
        offA[i] = (row * 4 + (quad ^ ((row >> 1) & 3))) * 8;
    }
#pragma unroll
    for (int j = 0; j < 4; ++j) {
        const int row = wn + j * 16 + l16;
        offB[j] = 4096 + (row * 4 + (quad ^ ((row >> 1) & 3))) * 8;
    }

    uint4 s0a0, s0a1, s0b0, s0b1;
    uint4 s1a0, s1a1, s1b0, s1b1;

    auto load0 = [&](int k) {
        s0a0 = *(const uint4*)(agp + k);        s0a1 = *(const uint4*)(agp + rowK + k);
        s0b0 = *(const uint4*)(bgp + k);        s0b1 = *(const uint4*)(bgp + rowK + k);
    };
    auto load1 = [&](int k) {
        s1a0 = *(const uint4*)(agp + k);        s1a1 = *(const uint4*)(agp + rowK + k);
        s1b0 = *(const uint4*)(bgp + k);        s1b1 = *(const uint4*)(bgp + rowK + k);
    };
    auto write0 = [&]() {   // always buf0
        *(uint4*)(sm + swz)         = s0a0;  *(uint4*)(sm + swz2)        = s0a1;
        *(uint4*)(sm + 4096 + swz)  = s0b0;  *(uint4*)(sm + 4096 + swz2) = s0b1;
    };
    auto write1 = [&]() {   // always buf1
        bf16* base = sm + 8192;
        *(uint4*)(base + swz)         = s1a0;  *(uint4*)(base + swz2)        = s1a1;
        *(uint4*)(base + 4096 + swz)  = s1b0;  *(uint4*)(base + 4096 + swz2) = s1b1;
    };
    auto compute = [&](const bf16* s) {
        bf16x8 af[4], bfr[4];
#pragma unroll
        for (int i = 0; i < 4; ++i) af[i] = *(const bf16x8*)(s + offA[i]);
#pragma unroll
        for (int j = 0; j < 4; ++j) bfr[j] = *(const bf16x8*)(s + offB[j]);
#pragma unroll
        for (int i = 0; i < 4; ++i)
#pragma unroll
            for (int j = 0; j < 4; ++j)   // swapped: D row=n, col=m
                acc[i][j] = __builtin_amdgcn_mfma_f32_16x16x32_bf16(bfr[j], af[i], acc[i][j], 0, 0, 0);
    };

    const int nk = K >> 5;
    load0(0);
    load1(32);
    write0();
    load0(64);
    __syncthreads();

    for (int kk = 0; kk < nk; kk += 2) {
        if (kk + 1 < nk) {
            write1();
            if (kk + 3 < nk) load1((kk + 3) * 32);
        }
        compute(sm);
        if (kk + 1 < nk) {
            __syncthreads();
            if (kk + 2 < nk) {
                write0();
                if (kk + 4 < nk) load0((kk + 4) * 32);
            }
            compute(sm + 8192);
            if (kk + 2 < nk) __syncthreads();
        }
    }

    bf16*  Cb = (bf16*)Cout;
    float* Cf = (float*)Cout;
    const bool vblock = SPLIT_V && (n0 >= 2048);
#pragma unroll
    for (int i = 0; i < 4; ++i) {
        const long gm = m0 + wm + i * 16 + l16;
#pragma unroll
        for (int j = 0; j < 4; ++j) {
            const int nloc = wn + j * 16 + quad * 4;
            const long n = n0 + nloc;
            const float4 bv = *(const float4*)(bias + n);
            float v[4];
#pragma unroll
            for (int r = 0; r < 4; ++r) v[r] = acc[i][j][r] + (&bv.x)[r];
            if (vblock) {
                const int bb = (int)(gm >> 11), tok = (int)(gm & 2047);
                const int nv = (int)(n - 2048);
                const int h = nv >> 6, d0 = nv & 63;
                bf16* dst = Vtb + ((size_t)(bb * 16 + h) * 64 + d0) * T_SEQ + tok;
#pragma unroll
                for (int r = 0; r < 4; ++r) dst[(size_t)r * T_SEQ] = (bf16)v[r];
            } else if (OUT_BF16) {
                bf16x4 o;
#pragma unroll
                for (int r = 0; r < 4; ++r) o[r] = (bf16)v[r];
                *(bf16x4*)(Cb + gm * ldC + n) = o;
            } else {
                float4 o;
#pragma unroll
                for (int r = 0; r < 4; ++r) (&o.x)[r] = v[r];
                *(float4*)(Cf + gm * ldC + n) = o;
            }
        }
    }
}

// ---------------------------------------------------------------------------
// Causal flash attention  [r6/r9 verbatim — best measured ~75 us].
// ---------------------------------------------------------------------------
__global__ __launch_bounds__(256, 3)
void attn_kernel(const bf16* __restrict__ qk, const bf16* __restrict__ vtb,
                 bf16* __restrict__ Out) {
    const int bh = blockIdx.x;
    const int qt = 15 - (int)blockIdx.y;    // heavy tiles first
    const int b = bh >> 4, h = bh & 15;
    const int t = threadIdx.x;
    const int wave = t >> 6, lane = t & 63, quad = lane >> 4, l16 = lane & 15;
    const int wq = wave * 32;
    const int q0 = qt * 128;

    __shared__ bf16 Ks[2][4096];
    __shared__ bf16 VTs[2][4096];
    __shared__ bf16 Ps[8192];

    const bf16* Qg = qk + (size_t)b * T_SEQ * QK_LD + h * 64;
    const bf16* Kg = Qg + 1024;
    const bf16* vth = vtb + (size_t)bh * 64 * T_SEQ;

    for (int c = t; c < 1024; c += 256) {
        const int row = c >> 3, kb = c & 7;
        *(uint4*)(Ps + row * 64 + (((kb ^ (row & 7)) << 3))) =
            *(const uint4*)(Qg + (size_t)(q0 + row) * QK_LD + kb * 8);
    }
    __syncthreads();
    const float qsc = 0.125f * 1.4426950408889634f;
    bf16x8 qf[2][2];
#pragma unroll
    for (int jt = 0; jt < 2; ++jt)
#pragma unroll
        for (int s = 0; s < 2; ++s) {
            const int row = wq + jt * 16 + l16;
            bf16x8 v = *(const bf16x8*)(Ps + row * 64 + (((s * 4 + quad) ^ (row & 7)) << 3));
#pragma unroll
            for (int e = 0; e < 8; ++e) v[e] = (bf16)((float)v[e] * qsc);
            qf[jt][s] = v;
        }

    const int sr = t >> 3;
    const int skb = (t & 7) ^ (sr & 7);
    const bf16* kp0 = Kg + (size_t)sr * QK_LD + skb * 8;
    const bf16* kp1 = kp0 + (size_t)32 * QK_LD;
    const bf16* vp0 = vth + (size_t)sr * T_SEQ + skb * 8;
    const bf16* vp1 = vp0 + (size_t)32 * T_SEQ;

    int offKV[4][2];
#pragma unroll
    for (int it = 0; it < 4; ++it)
#pragma unroll
        for (int s = 0; s < 2; ++s) {
            const int row = it * 16 + l16;
            offKV[it][s] = row * 64 + (((s * 4 + quad) ^ (row & 7)) << 3);
        }

    f32x4 oacc[4][2] = {};
    float lsum[2] = {0.f, 0.f};
    const int nkt = qt * 2 + 2;

    uint4 kr0 = *(const uint4*)kp0, kr1 = *(const uint4*)kp1;
    uint4 vr0 = *(const uint4*)vp0, vr1 = *(const uint4*)vp1;

    for (int kt = 0; kt < nkt; ++kt) {
        const int k0 = kt * 64;
        bf16* kb_ = Ks[kt & 1];
        bf16* vb_ = VTs[kt & 1];
        *(uint4*)(kb_ + t * 8)        = kr0;
        *(uint4*)(kb_ + 2048 + t * 8) = kr1;
        *(uint4*)(vb_ + t * 8)        = vr0;
        *(uint4*)(vb_ + 2048 + t * 8) = vr1;
        __syncthreads();

        if (kt + 1 < nkt) {
            const int kn = k0 + 64;
            kr0 = *(const uint4*)(kp0 + (size_t)kn * QK_LD);
            kr1 = *(const uint4*)(kp1 + (size_t)kn * QK_LD);
            vr0 = *(const uint4*)(vp0 + kn);
            vr1 = *(const uint4*)(vp1 + kn);
        }

        f32x4 sacc[4][2] = {};
#pragma unroll
        for (int s = 0; s < 2; ++s) {
            bf16x8 kf[4];
#pragma unroll
            for (int it = 0; it < 4; ++it)
                kf[it] = *(const bf16x8*)(kb_ + offKV[it][s]);
#pragma unroll
            for (int it = 0; it < 4; ++it)
#pragma unroll
                for (int jt = 0; jt < 2; ++jt)
                    sacc[it][jt] = __builtin_amdgcn_mfma_f32_16x16x32_bf16(kf[it], qf[jt][s], sacc[it][jt], 0, 0, 0);
        }

        const bool need_mask = (kt >= 2 * qt);
#pragma unroll
        for (int it = 0; it < 4; ++it)
#pragma unroll
            for (int jt = 0; jt < 2; ++jt) {
                const int prow = wq + jt * 16 + l16;
                bf16x4 pb;
                if (need_mask) {
                    const int qrow = q0 + prow;
                    const int kbase = k0 + it * 16 + quad * 4;
#pragma unroll
                    for (int r = 0; r < 4; ++r) {
                        const float e = __ocml_native_exp2_f32(sacc[it][jt][r]);
                        const float p = (kbase + r > qrow) ? 0.f : e;
                        lsum[jt] += p;
                        pb[r] = (bf16)p;
                    }
                } else {
#pragma unroll
                    for (int r = 0; r < 4; ++r) {
                        const float p = __ocml_native_exp2_f32(sacc[it][jt][r]);
                        lsum[jt] += p;
                        pb[r] = (bf16)p;
                    }
                }
                *(bf16x4*)(Ps + prow * 64 +
                           (((it * 2 + (quad >> 1)) ^ (prow & 7)) << 3) + ((quad & 1) << 2)) = pb;
            }

#pragma unroll
        for (int s2 = 0; s2 < 2; ++s2) {
            bf16x8 vf[4], pf[2];
#pragma unroll
            for (int it2 = 0; it2 < 4; ++it2)
                vf[it2] = *(const bf16x8*)(vb_ + offKV[it2][s2]);
#pragma unroll
            for (int jt = 0; jt < 2; ++jt) {
                const int prow = wq + jt * 16 + l16;
                pf[jt] = *(const bf16x8*)(Ps + prow * 64 + (((s2 * 4 + quad) ^ (prow & 7)) << 3));
            }
#pragma unroll
            for (int it2 = 0; it2 < 4; ++it2)
#pragma unroll
                for (int jt = 0; jt < 2; ++jt)
                    oacc[it2][jt] = __builtin_amdgcn_mfma_f32_16x16x32_bf16(vf[it2], pf[jt], oacc[it2][jt], 0, 0, 0);
        }
    }

    float inv[2];
#pragma unroll
    for (int jt = 0; jt < 2; ++jt) {
        float l = lsum[jt];
        l += __shfl_xor(l, 16);
        l += __shfl_xor(l, 32);
        inv[jt] = 1.0f / l;
    }
#pragma unroll
    for (int it2 = 0; it2 < 4; ++it2)
#pragma unroll
        for (int jt = 0; jt < 2; ++jt) {
            bf16x4 ob;
#pragma unroll
            for (int r = 0; r < 4; ++r) ob[r] = (bf16)(oacc[it2][jt][r] * inv[jt]);
            const int qrow = q0 + wq + jt * 16 + l16;
            const int dcol = h * 64 + it2 * 16 + quad * 4;
            *(bf16x4*)&Out[(size_t)(b * T_SEQ + qrow) * 1024 + dcol] = ob;
        }
}

// ---------------------------------------------------------------------------
extern "C" void kernel_launch(void* const* d_in, const int* in_sizes, int n_in,
                              void* d_out, int out_size, void* d_ws, size_t ws_size,
                              hipStream_t stream) {
    const float* x     = (const float*)d_in[0];
    const float* W_qkv = (const float*)d_in[1];
    const float* b_qkv = (const float*)d_in[2];
    const float* W_out = (const float*)d_in[3];
    const float* b_out = (const float*)d_in[4];
    float* out = (float*)d_out;

    char* ws = (char*)d_ws;
    bf16* xb   = (bf16*)ws; ws += (size_t)8192 * 1024 * 2;
    bf16* wtq  = (bf16*)ws; ws += (size_t)3072 * 1024 * 2;
    bf16* wto  = (bf16*)ws; ws += (size_t)1024 * 1024 * 2;
    bf16* qkb  = (bf16*)ws; ws += (size_t)8192 * 2048 * 2;    // Q|K rows
    bf16* vtb  = (bf16*)ws; ws += (size_t)64 * 64 * 2048 * 2; // V^T per bh
    bf16* aout = (bf16*)ws; ws += (size_t)8192 * 1024 * 2;

    prep_kernel<<<8192 + 4096, 256, 0, stream>>>(x, xb, W_qkv, wtq, W_out, wto);

    gemm256<true, true><<<dim3(12, 32), 512, 0, stream>>>(
        xb, wtq, b_qkv, (void*)qkb, vtb, 8192, 3072, 1024, 2048);
    attn_kernel<<<dim3(64, 16), 256, 0, stream>>>(qkb, vtb, aout);
    gemm_bt<false, false><<<dim3(8, 64), 256, 0, stream>>>(
        aout, wto, b_out, (void*)out, nullptr, 8192, 1024, 1024, 1024);
}

// Round 2
// 240.291 us; speedup vs baseline: 1.0434x; 1.0434x over previous
//
#include <hip/hip_runtime.h>

typedef __bf16 bf16;
typedef __bf16 bf16x4 __attribute__((ext_vector_type(4)));
typedef __bf16 bf16x8 __attribute__((ext_vector_type(8)));
typedef float f32x4 __attribute__((ext_vector_type(4)));

#define T_SEQ 2048
#define QK_LD 2048

extern "C" __device__ float __ocml_native_exp2_f32(float);   // raw v_exp_f32

#define GLOAD16(gp, lp)                                                        \
  __builtin_amdgcn_global_load_lds(                                            \
      (const __attribute__((address_space(1))) unsigned int*)(gp),             \
      (__attribute__((address_space(3))) unsigned int*)(lp), 16, 0, 0)

// ---------------------------------------------------------------------------
// Fused prep (one dispatch, 256-thr blocks):
//   blocks [0, 8192)        : x (fp32, 8192x1024) -> xb bf16
//   blocks [8192, 8192+3072): W_qkv (1024x3072) -> wtq (3072x1024) bf16
//   blocks [+3072, +4096)   : W_out (1024x1024) -> wto (1024x1024) bf16
// ---------------------------------------------------------------------------
__global__ void prep_kernel(const float* __restrict__ x, bf16* __restrict__ xb,
                            const float* __restrict__ Wq, bf16* __restrict__ Wtq,
                            const float* __restrict__ Wo, bf16* __restrict__ Wto) {
    __shared__ float tile[32][33];
    const int t = threadIdx.x;
    if (blockIdx.x < 8192) {
        const int i = (blockIdx.x * 256 + t) * 4;
        const float4 f = *(const float4*)(x + i);
        bf16x4 o;
        o.x = (bf16)f.x; o.y = (bf16)f.y; o.z = (bf16)f.z; o.w = (bf16)f.w;
        *(bf16x4*)(xb + i) = o;
        return;
    }
    const int bid = blockIdx.x - 8192;            // [0, 4096)
    const int xblk = bid & 127, yblk = bid >> 7;  // 128 x 32 tiles of 32x32
    const bool isQ = xblk < 96;
    const float* W = isQ ? Wq : Wo;
    bf16* Wt = isQ ? Wtq : Wto;
    const int C = isQ ? 3072 : 1024;
    const int R = 1024;
    const int bx = (isQ ? xblk : (xblk - 96)) * 32;
    const int by = yblk * 32;
    const int tx = t & 31, ty = t >> 5;
#pragma unroll
    for (int i = 0; i < 32; i += 8)
        tile[ty + i][tx] = W[(size_t)(by + ty + i) * C + bx + tx];
    __syncthreads();
#pragma unroll
    for (int i = 0; i < 32; i += 8)
        Wt[(size_t)(bx + ty + i) * R + by + tx] = (bf16)tile[tx][ty + i];
}

// ---------------------------------------------------------------------------
// 256x256 8-phase GEMM (T2+T3+T4+T5), round-1 fix: REGISTER-RESIDENT
// fragments. Round-0 re-read all A/B frags every phase (48 ds_read_b128 per
// K-tile/wave) -> LDS-read-bound (MfmaUtil 24%). Now each fragment is read
// exactly once per K-tile (24 reads: p0 A0+B0, p1 A1, p2 B1, p3 none) and
// held in named arrays fA0/fA1/fB0/fB1 (96 VGPR) across the 4 quadrant
// phases. vmcnt drain order already lands each half right before the phase
// that reads it (A1 after p0, B1 after p1, next A0/B0 after p3) -> wait
// strings unchanged. Staging: global_load_lds dwordx4, linear LDS dest,
// XOR-swizzle (c ^= row&7, 16B chunks) on the GLOBAL source (rule #21).
// Raw s_barrier (never __syncthreads: vmcnt(0) drain = the m97 stall).
// ---------------------------------------------------------------------------
template <bool OUT_BF16, bool SPLIT_V>
__global__ __launch_bounds__(512, 2)
void gemm256(const bf16* __restrict__ A, const bf16* __restrict__ Bt,
             const float* __restrict__ bias, void* __restrict__ Cout,
             bf16* __restrict__ Vtb, int M, int N, int K, int ldC) {
    __shared__ bf16 sm[65536];   // 128 KiB

    const int t = threadIdx.x;
    const int lane = t & 63, quad = lane >> 4, l16 = lane & 15;
    const int wv = t >> 6;
    const int wm = (wv >> 2) * 64;   // row base within an A half (2 M-wave-groups)
    const int wn = (wv & 3) * 32;    // row base within a B half (4 N-wave-groups)
    const long m0 = (long)blockIdx.y * 256;
    const long n0 = (long)blockIdx.x * 256;
    (void)M; (void)N;

    f32x4 acc[2][2][4][2] = {};      // [mq][nq][i][j]

    // --- staging source coords: linear chunk l = q*512 + t ------------------
    // row = q*64 + (t>>3); stored chunk c' = t&7 holds logical c = c'^(row&7)
    const int srow = t >> 3;
    const int scol = ((t & 7) ^ ((t >> 3) & 7)) * 8;
    const bf16* agp = A  + (m0 + srow) * (long)K + scol;
    const bf16* bgp = Bt + (n0 + srow) * (long)K + scol;
    const long rowK64  = (long)64 * K;
    const long rowK128 = (long)128 * K;
    bf16* ldst = sm + wv * 512;      // + buf*32768 + oper*16384 + half*8192 + q*4096

    auto stage = [&](int buf, int oper, int half, int kt) {
        const bf16* src = (oper ? bgp : agp) + (long)kt * 64 + (half ? rowK128 : 0);
        bf16* dst = ldst + buf * 32768 + oper * 16384 + half * 8192;
        GLOAD16(src, dst);                      // rows [0,64) of the half
        GLOAD16(src + rowK64, dst + 4096);      // rows [64,128)
    };

    // --- fragment LDS offsets (within a half base) --------------------------
    int offA[4][2], offB[2][2];
#pragma unroll
    for (int i = 0; i < 4; ++i)
#pragma unroll
        for (int ks = 0; ks < 2; ++ks) {
            const int r = wm + i * 16 + l16;
            offA[i][ks] = r * 64 + (((ks * 4 + quad) ^ (r & 7)) << 3);
        }
#pragma unroll
    for (int j = 0; j < 2; ++j)
#pragma unroll
        for (int ks = 0; ks < 2; ++ks) {
            const int r = wn + j * 16 + l16;
            offB[j][ks] = r * 64 + (((ks * 4 + quad) ^ (r & 7)) << 3);
        }

    // register-resident fragments (held across the 4 quadrant phases)
    bf16x8 fA0[2][4], fA1[2][4];     // [ks][i]  — 64 VGPR
    bf16x8 fB0[2][2], fB1[2][2];     // [ks][j]  — 32 VGPR

#define PHASE(BUF, MQ, NQ, RDA, RDB, FA, FB, DOSTAGE, SOP, SHF, SKT, WAITSTR)  \
  do {                                                                         \
    const bf16* base_ = sm + (BUF) * 32768;                                    \
    if (RDA) {                                                                 \
        const bf16* sa_ = base_ + (MQ) * 8192;                                 \
        _Pragma("unroll") for (int ks = 0; ks < 2; ++ks)                       \
            _Pragma("unroll") for (int i = 0; i < 4; ++i)                      \
                FA[ks][i] = *(const bf16x8*)(sa_ + offA[i][ks]);               \
    }                                                                          \
    if (RDB) {                                                                 \
        const bf16* sbb_ = base_ + 16384 + (NQ) * 8192;                        \
        _Pragma("unroll") for (int ks = 0; ks < 2; ++ks)                       \
            _Pragma("unroll") for (int j = 0; j < 2; ++j)                      \
                FB[ks][j] = *(const bf16x8*)(sbb_ + offB[j][ks]);              \
    }                                                                          \
    if (DOSTAGE) stage((BUF) ^ 1, SOP, SHF, SKT);                              \
    __builtin_amdgcn_s_barrier();                                              \
    __builtin_amdgcn_s_setprio(1);                                             \
    _Pragma("unroll") for (int ks = 0; ks < 2; ++ks)                           \
        _Pragma("unroll") for (int i = 0; i < 4; ++i)                          \
            _Pragma("unroll") for (int j = 0; j < 2; ++j)                      \
                acc[MQ][NQ][i][j] = __builtin_amdgcn_mfma_f32_16x16x32_bf16(   \
                    FB[ks][j], FA[ks][i], acc[MQ][NQ][i][j], 0, 0, 0);         \
    __builtin_amdgcn_s_setprio(0);                                             \
    asm volatile(WAITSTR ::: "memory");                                        \
    __builtin_amdgcn_s_barrier();                                              \
    __builtin_amdgcn_sched_barrier(0);                                         \
  } while (0)

    const int nkt = K >> 6;          // K-tiles of 64

    // prologue: stage tile 0 (order A0,B0,A1,B1); first 4 loads must land
    stage(0, 0, 0, 0);
    stage(0, 1, 0, 0);
    stage(0, 0, 1, 0);
    stage(0, 1, 1, 0);
    asm volatile("s_waitcnt vmcnt(4)" ::: "memory");
    __builtin_amdgcn_s_barrier();
    __builtin_amdgcn_sched_barrier(0);

    for (int kt = 0; kt < nkt - 1; ++kt) {
        const int buf = kt & 1;
        const int kn = kt + 1;
        PHASE(buf, 0, 0, true,  true,  fA0, fB0, true, 0, 0, kn, "s_waitcnt vmcnt(4)");
        PHASE(buf, 1, 0, true,  false, fA1, fB0, true, 1, 0, kn, "s_waitcnt vmcnt(4)");
        PHASE(buf, 0, 1, false, true,  fA0, fB1, true, 0, 1, kn, "");
        PHASE(buf, 1, 1, false, false, fA1, fB1, true, 1, 1, kn, "s_waitcnt vmcnt(4)");
    }
    {   // last tile: no staging; drain counted 2 -> 0
        const int buf = (nkt - 1) & 1;
        PHASE(buf, 0, 0, true,  true,  fA0, fB0, false, 0, 0, 0, "s_waitcnt vmcnt(2)");
        PHASE(buf, 1, 0, true,  false, fA1, fB0, false, 0, 0, 0, "s_waitcnt vmcnt(0)");
        PHASE(buf, 0, 1, false, true,  fA0, fB1, false, 0, 0, 0, "");
        PHASE(buf, 1, 1, false, false, fA1, fB1, false, 0, 0, 0, "");
    }
#undef PHASE

    // --- epilogue (same swapped-D mapping as before: col=m via l16, row=n) --
    bf16*  Cb = (bf16*)Cout;
    float* Cf = (float*)Cout;
    const bool vblock = SPLIT_V && (n0 >= 2048);
#pragma unroll
    for (int mq = 0; mq < 2; ++mq)
#pragma unroll
    for (int i = 0; i < 4; ++i) {
        const long gm = m0 + mq * 128 + wm + i * 16 + l16;
#pragma unroll
        for (int nq = 0; nq < 2; ++nq)
#pragma unroll
        for (int j = 0; j < 2; ++j) {
            const long n = n0 + nq * 128 + wn + j * 16 + quad * 4;
            const float4 bv = *(const float4*)(bias + n);
            float v[4];
#pragma unroll
            for (int r = 0; r < 4; ++r) v[r] = acc[mq][nq][i][j][r] + (&bv.x)[r];
            if (vblock) {
                const int bb = (int)(gm >> 11), tok = (int)(gm & 2047);
                const int nv = (int)(n - 2048);
                const int h = nv >> 6, d0 = nv & 63;
                bf16* dst = Vtb + ((size_t)(bb * 16 + h) * 64 + d0) * T_SEQ + tok;
#pragma unroll
                for (int r = 0; r < 4; ++r) dst[(size_t)r * T_SEQ] = (bf16)v[r];
            } else if (OUT_BF16) {
                bf16x4 o;
#pragma unroll
                for (int r = 0; r < 4; ++r) o[r] = (bf16)v[r];
                *(bf16x4*)(Cb + gm * ldC + n) = o;
            } else {
                float4 o;
#pragma unroll
                for (int r = 0; r < 4; ++r) (&o.x)[r] = v[r];
                *(float4*)(Cf + gm * ldC + n) = o;
            }
        }
    }
}

// ---------------------------------------------------------------------------
// OLD 128x128 GEMM — kept for the output projection (N=1024: a 256² grid
// would be only 128 blocks = half-idle GPU). [r6/r9 verbatim]
// ---------------------------------------------------------------------------
template <bool OUT_BF16, bool SPLIT_V>
__global__ __launch_bounds__(256, 3)
void gemm_bt(const bf16* __restrict__ A, const bf16* __restrict__ Bt,
             const float* __restrict__ bias, void* __restrict__ Cout,
             bf16* __restrict__ Vtb, int M, int N, int K, int ldC) {
    __shared__ bf16 sm[16384];   // 2 bufs x (A 4096 + B 4096 elems) = 32 KB

    const int t = threadIdx.x;
    const int lane = t & 63, quad = lane >> 4, l16 = lane & 15;
    const int wave = t >> 6;
    const int wm = (wave >> 1) * 64;
    const int wn = (wave & 1) * 64;
    const long m0 = (long)blockIdx.y * 128;
    const long n0 = (long)blockIdx.x * 128;

    f32x4 acc[4][4] = {};

    const int sr = t >> 2, sc = t & 3;
    const int swz  = (sr * 4 + (sc ^ ((sr >> 1) & 3))) * 8;
    const int swz2 = ((sr + 64) * 4 + (sc ^ ((sr >> 1) & 3))) * 8;
    const bf16* agp = A  + (m0 + sr) * (long)K + sc * 8;
    const bf16* bgp = Bt + (n0 + sr) * (long)K + sc * 8;
    const long rowK = (long)64 * K;

    int offA[4], offB[4];
#pragma unroll
    for (int i = 0; i < 4; ++i) {
        const int row = wm + i * 16 + l16;
        offA[i] = (row * 4 + (quad ^ ((row >> 1) & 3))) * 8;
    }
#pragma unroll
    for (int j = 0; j < 4; ++j) {
        const int row = wn + j * 16 + l16;
        offB[j] = 4096 + (row * 4 + (quad ^ ((row >> 1) & 3))) * 8;
    }

    uint4 s0a0, s0a1, s0b0, s0b1;
    uint4 s1a0, s1a1, s1b0, s1b1;

    auto load0 = [&](int k) {
        s0a0 = *(const uint4*)(agp + k);        s0a1 = *(const uint4*)(agp + rowK + k);
        s0b0 = *(const uint4*)(bgp + k);        s0b1 = *(const uint4*)(bgp + rowK + k);
    };
    auto load1 = [&](int k) {
        s1a0 = *(const uint4*)(agp + k);        s1a1 = *(const uint4*)(agp + rowK + k);
        s1b0 = *(const uint4*)(bgp + k);        s1b1 = *(const uint4*)(bgp + rowK + k);
    };
    auto write0 = [&]() {   // always buf0
        *(uint4*)(sm + swz)         = s0a0;  *(uint4*)(sm + swz2)        = s0a1;
        *(uint4*)(sm + 4096 + swz)  = s0b0;  *(uint4*)(sm + 4096 + swz2) = s0b1;
    };
    auto write1 = [&]() {   // always buf1
        bf16* base = sm + 8192;
        *(uint4*)(base + swz)         = s1a0;  *(uint4*)(base + swz2)        = s1a1;
        *(uint4*)(base + 4096 + swz)  = s1b0;  *(uint4*)(base + 4096 + swz2) = s1b1;
    };
    auto compute = [&](const bf16* s) {
        bf16x8 af[4], bfr[4];
#pragma unroll
        for (int i = 0; i < 4; ++i) af[i] = *(const bf16x8*)(s + offA[i]);
#pragma unroll
        for (int j = 0; j < 4; ++j) bfr[j] = *(const bf16x8*)(s + offB[j]);
#pragma unroll
        for (int i = 0; i < 4; ++i)
#pragma unroll
            for (int j = 0; j < 4; ++j)   // swapped: D row=n, col=m
                acc[i][j] = __builtin_amdgcn_mfma_f32_16x16x32_bf16(bfr[j], af[i], acc[i][j], 0, 0, 0);
    };

    const int nk = K >> 5;
    load0(0);
    load1(32);
    write0();
    load0(64);
    __syncthreads();

    for (int kk = 0; kk < nk; kk += 2) {
        if (kk + 1 < nk) {
            write1();
            if (kk + 3 < nk) load1((kk + 3) * 32);
        }
        compute(sm);
        if (kk + 1 < nk) {
            __syncthreads();
            if (kk + 2 < nk) {
                write0();
                if (kk + 4 < nk) load0((kk + 4) * 32);
            }
            compute(sm + 8192);
            if (kk + 2 < nk) __syncthreads();
        }
    }

    bf16*  Cb = (bf16*)Cout;
    float* Cf = (float*)Cout;
    const bool vblock = SPLIT_V && (n0 >= 2048);
#pragma unroll
    for (int i = 0; i < 4; ++i) {
        const long gm = m0 + wm + i * 16 + l16;
#pragma unroll
        for (int j = 0; j < 4; ++j) {
            const int nloc = wn + j * 16 + quad * 4;
            const long n = n0 + nloc;
            const float4 bv = *(const float4*)(bias + n);
            float v[4];
#pragma unroll
            for (int r = 0; r < 4; ++r) v[r] = acc[i][j][r] + (&bv.x)[r];
            if (vblock) {
                const int bb = (int)(gm >> 11), tok = (int)(gm & 2047);
                const int nv = (int)(n - 2048);
                const int h = nv >> 6, d0 = nv & 63;
                bf16* dst = Vtb + ((size_t)(bb * 16 + h) * 64 + d0) * T_SEQ + tok;
#pragma unroll
                for (int r = 0; r < 4; ++r) dst[(size_t)r * T_SEQ] = (bf16)v[r];
            } else if (OUT_BF16) {
                bf16x4 o;
#pragma unroll
                for (int r = 0; r < 4; ++r) o[r] = (bf16)v[r];
                *(bf16x4*)(Cb + gm * ldC + n) = o;
            } else {
                float4 o;
#pragma unroll
                for (int r = 0; r < 4; ++r) (&o.x)[r] = v[r];
                *(float4*)(Cf + gm * ldC + n) = o;
            }
        }
    }
}

// ---------------------------------------------------------------------------
// Causal flash attention  [r6/r9 verbatim — best measured ~75 us].
// ---------------------------------------------------------------------------
__global__ __launch_bounds__(256, 3)
void attn_kernel(const bf16* __restrict__ qk, const bf16* __restrict__ vtb,
                 bf16* __restrict__ Out) {
    const int bh = blockIdx.x;
    const int qt = 15 - (int)blockIdx.y;    // heavy tiles first
    const int b = bh >> 4, h = bh & 15;
    const int t = threadIdx.x;
    const int wave = t >> 6, lane = t & 63, quad = lane >> 4, l16 = lane & 15;
    const int wq = wave * 32;
    const int q0 = qt * 128;

    __shared__ bf16 Ks[2][4096];
    __shared__ bf16 VTs[2][4096];
    __shared__ bf16 Ps[8192];

    const bf16* Qg = qk + (size_t)b * T_SEQ * QK_LD + h * 64;
    const bf16* Kg = Qg + 1024;
    const bf16* vth = vtb + (size_t)bh * 64 * T_SEQ;

    for (int c = t; c < 1024; c += 256) {
        const int row = c >> 3, kb = c & 7;
        *(uint4*)(Ps + row * 64 + (((kb ^ (row & 7)) << 3))) =
            *(const uint4*)(Qg + (size_t)(q0 + row) * QK_LD + kb * 8);
    }
    __syncthreads();
    const float qsc = 0.125f * 1.4426950408889634f;
    bf16x8 qf[2][2];
#pragma unroll
    for (int jt = 0; jt < 2; ++jt)
#pragma unroll
        for (int s = 0; s < 2; ++s) {
            const int row = wq + jt * 16 + l16;
            bf16x8 v = *(const bf16x8*)(Ps + row * 64 + (((s * 4 + quad) ^ (row & 7)) << 3));
#pragma unroll
            for (int e = 0; e < 8; ++e) v[e] = (bf16)((float)v[e] * qsc);
            qf[jt][s] = v;
        }

    const int sr = t >> 3;
    const int skb = (t & 7) ^ (sr & 7);
    const bf16* kp0 = Kg + (size_t)sr * QK_LD + skb * 8;
    const bf16* kp1 = kp0 + (size_t)32 * QK_LD;
    const bf16* vp0 = vth + (size_t)sr * T_SEQ + skb * 8;
    const bf16* vp1 = vp0 + (size_t)32 * T_SEQ;

    int offKV[4][2];
#pragma unroll
    for (int it = 0; it < 4; ++it)
#pragma unroll
        for (int s = 0; s < 2; ++s) {
            const int row = it * 16 + l16;
            offKV[it][s] = row * 64 + (((s * 4 + quad) ^ (row & 7)) << 3);
        }

    f32x4 oacc[4][2] = {};
    float lsum[2] = {0.f, 0.f};
    const int nkt = qt * 2 + 2;

    uint4 kr0 = *(const uint4*)kp0, kr1 = *(const uint4*)kp1;
    uint4 vr0 = *(const uint4*)vp0, vr1 = *(const uint4*)vp1;

    for (int kt = 0; kt < nkt; ++kt) {
        const int k0 = kt * 64;
        bf16* kb_ = Ks[kt & 1];
        bf16* vb_ = VTs[kt & 1];
        *(uint4*)(kb_ + t * 8)        = kr0;
        *(uint4*)(kb_ + 2048 + t * 8) = kr1;
        *(uint4*)(vb_ + t * 8)        = vr0;
        *(uint4*)(vb_ + 2048 + t * 8) = vr1;
        __syncthreads();

        if (kt + 1 < nkt) {
            const int kn = k0 + 64;
            kr0 = *(const uint4*)(kp0 + (size_t)kn * QK_LD);
            kr1 = *(const uint4*)(kp1 + (size_t)kn * QK_LD);
            vr0 = *(const uint4*)(vp0 + kn);
            vr1 = *(const uint4*)(vp1 + kn);
        }

        f32x4 sacc[4][2] = {};
#pragma unroll
        for (int s = 0; s < 2; ++s) {
            bf16x8 kf[4];
#pragma unroll
            for (int it = 0; it < 4; ++it)
                kf[it] = *(const bf16x8*)(kb_ + offKV[it][s]);
#pragma unroll
            for (int it = 0; it < 4; ++it)
#pragma unroll
                for (int jt = 0; jt < 2; ++jt)
                    sacc[it][jt] = __builtin_amdgcn_mfma_f32_16x16x32_bf16(kf[it], qf[jt][s], sacc[it][jt], 0, 0, 0);
        }

        const bool need_mask = (kt >= 2 * qt);
#pragma unroll
        for (int it = 0; it < 4; ++it)
#pragma unroll
            for (int jt = 0; jt < 2; ++jt) {
                const int prow = wq + jt * 16 + l16;
                bf16x4 pb;
                if (need_mask) {
                    const int qrow = q0 + prow;
                    const int kbase = k0 + it * 16 + quad * 4;
#pragma unroll
                    for (int r = 0; r < 4; ++r) {
                        const float e = __ocml_native_exp2_f32(sacc[it][jt][r]);
                        const float p = (kbase + r > qrow) ? 0.f : e;
                        lsum[jt] += p;
                        pb[r] = (bf16)p;
                    }
                } else {
#pragma unroll
                    for (int r = 0; r < 4; ++r) {
                        const float p = __ocml_native_exp2_f32(sacc[it][jt][r]);
                        lsum[jt] += p;
                        pb[r] = (bf16)p;
                    }
                }
                *(bf16x4*)(Ps + prow * 64 +
                           (((it * 2 + (quad >> 1)) ^ (prow & 7)) << 3) + ((quad & 1) << 2)) = pb;
            }

#pragma unroll
        for (int s2 = 0; s2 < 2; ++s2) {
            bf16x8 vf[4], pf[2];
#pragma unroll
            for (int it2 = 0; it2 < 4; ++it2)
                vf[it2] = *(const bf16x8*)(vb_ + offKV[it2][s2]);
#pragma unroll
            for (int jt = 0; jt < 2; ++jt) {
                const int prow = wq + jt * 16 + l16;
                pf[jt] = *(const bf16x8*)(Ps + prow * 64 + (((s2 * 4 + quad) ^ (prow & 7)) << 3));
            }
#pragma unroll
            for (int it2 = 0; it2 < 4; ++it2)
#pragma unroll
                for (int jt = 0; jt < 2; ++jt)
                    oacc[it2][jt] = __builtin_amdgcn_mfma_f32_16x16x32_bf16(vf[it2], pf[jt], oacc[it2][jt], 0, 0, 0);
        }
    }

    float inv[2];
#pragma unroll
    for (int jt = 0; jt < 2; ++jt) {
        float l = lsum[jt];
        l += __shfl_xor(l, 16);
        l += __shfl_xor(l, 32);
        inv[jt] = 1.0f / l;
    }
#pragma unroll
    for (int it2 = 0; it2 < 4; ++it2)
#pragma unroll
        for (int jt = 0; jt < 2; ++jt) {
            bf16x4 ob;
#pragma unroll
            for (int r = 0; r < 4; ++r) ob[r] = (bf16)(oacc[it2][jt][r] * inv[jt]);
            const int qrow = q0 + wq + jt * 16 + l16;
            const int dcol = h * 64 + it2 * 16 + quad * 4;
            *(bf16x4*)&Out[(size_t)(b * T_SEQ + qrow) * 1024 + dcol] = ob;
        }
}

// ---------------------------------------------------------------------------
extern "C" void kernel_launch(void* const* d_in, const int* in_sizes, int n_in,
                              void* d_out, int out_size, void* d_ws, size_t ws_size,
                              hipStream_t stream) {
    const float* x     = (const float*)d_in[0];
    const float* W_qkv = (const float*)d_in[1];
    const float* b_qkv = (const float*)d_in[2];
    const float* W_out = (const float*)d_in[3];
    const float* b_out = (const float*)d_in[4];
    float* out = (float*)d_out;

    char* ws = (char*)d_ws;
    bf16* xb   = (bf16*)ws; ws += (size_t)8192 * 1024 * 2;
    bf16* wtq  = (bf16*)ws; ws += (size_t)3072 * 1024 * 2;
    bf16* wto  = (bf16*)ws; ws += (size_t)1024 * 1024 * 2;
    bf16* qkb  = (bf16*)ws; ws += (size_t)8192 * 2048 * 2;    // Q|K rows
    bf16* vtb  = (bf16*)ws; ws += (size_t)64 * 64 * 2048 * 2; // V^T per bh
    bf16* aout = (bf16*)ws; ws += (size_t)8192 * 1024 * 2;

    prep_kernel<<<8192 + 4096, 256, 0, stream>>>(x, xb, W_qkv, wtq, W_out, wto);

    gemm256<true, true><<<dim3(12, 32), 512, 0, stream>>>(
        xb, wtq, b_qkv, (void*)qkb, vtb, 8192, 3072, 1024, 2048);
    attn_kernel<<<dim3(64, 16), 256, 0, stream>>>(qkb, vtb, aout);
    gemm_bt<false, false><<<dim3(8, 64), 256, 0, stream>>>(
        aout, wto, b_out, (void*)out, nullptr, 8192, 1024, 1024, 1024);
}